// Round 1
// baseline (525.216 us; speedup 1.0000x reference)
//
#include <hip/hip_runtime.h>
#include <hip/hip_bf16.h>

// Problem constants (linear_nce): N=8192, H=1024, V=50257, K=4096
#define NROWS 8192
#define HDIM  1024
#define VDIM  50257
#define KNOISE 4096

typedef short  bf16x8 __attribute__((ext_vector_type(8)));
typedef float  f32x4  __attribute__((ext_vector_type(4)));

__device__ __forceinline__ unsigned short f2bf(float x) {
    // round-to-nearest-even fp32 -> bf16 (inputs are finite; no NaN handling needed)
    union { float f; unsigned int u; } v; v.f = x;
    unsigned int r = (v.u + 0x7fffu + ((v.u >> 16) & 1u)) >> 16;
    return (unsigned short)r;
}

// ---------------------------------------------------------------------------
// Kernel 1: convert input [8192x1024] fp32 -> bf16 (ws)
__global__ void conv_input_kernel(const float* __restrict__ in,
                                  unsigned short* __restrict__ out) {
    int idx = blockIdx.x * blockDim.x + threadIdx.x;   // one float4 per thread
    const float4* in4 = (const float4*)in;
    float4 v = in4[idx];
    ushort4 o;
    o.x = f2bf(v.x); o.y = f2bf(v.y); o.z = f2bf(v.z); o.w = f2bf(v.w);
    ((ushort4*)out)[idx] = o;
}

// ---------------------------------------------------------------------------
// Kernel 2: gather weight[noise] rows -> bf16 (ws); also bias[noise], unigram[noise]
__global__ void gather_noise_kernel(const float* __restrict__ weight,
                                    const float* __restrict__ bias,
                                    const float* __restrict__ unigram,
                                    const int* __restrict__ noise,
                                    unsigned short* __restrict__ wn,
                                    float* __restrict__ bn,
                                    float* __restrict__ un) {
    int r = blockIdx.x;                // 0..4095
    int idx = noise[r];
    const float4* src = (const float4*)(weight + (size_t)idx * HDIM);
    ushort4* dst = (ushort4*)(wn + (size_t)r * HDIM);
    int t = threadIdx.x;               // 256 threads, 256 float4 chunks per row
    float4 v = src[t];
    ushort4 o;
    o.x = f2bf(v.x); o.y = f2bf(v.y); o.z = f2bf(v.z); o.w = f2bf(v.w);
    dst[t] = o;
    if (t == 0) { bn[r] = bias[idx]; un[r] = unigram[idx]; }
}

// ---------------------------------------------------------------------------
// Kernel 3: pmt / pnt — exact fp32 dot per row
__global__ void pmt_kernel(const float* __restrict__ in,
                           const float* __restrict__ weight,
                           const float* __restrict__ bias,
                           const float* __restrict__ unigram,
                           const int* __restrict__ target,
                           float* __restrict__ out_pmt,
                           float* __restrict__ out_pnt) {
    int row = blockIdx.x;
    int t   = target[row];
    int tid = threadIdx.x;
    const float4* a4 = (const float4*)(in + (size_t)row * HDIM);
    const float4* w4 = (const float4*)(weight + (size_t)t * HDIM);
    float4 a = a4[tid];
    float4 w = w4[tid];
    float s = a.x * w.x + a.y * w.y + a.z * w.z + a.w * w.w;
    #pragma unroll
    for (int off = 32; off > 0; off >>= 1) s += __shfl_down(s, off);
    __shared__ float red[4];
    if ((tid & 63) == 0) red[tid >> 6] = s;
    __syncthreads();
    if (tid == 0) {
        float tot = red[0] + red[1] + red[2] + red[3];
        out_pmt[row] = expf(tot + bias[t]);
        out_pnt[row] = unigram[t];
    }
}

// ---------------------------------------------------------------------------
// Kernel 4: pmn = exp(A @ Bt^T + bn) and pnn = broadcast(un)
// A [8192x1024] bf16 row-major, Bt [4096x1024] bf16 row-major (gathered noise rows).
// 128x128 block tile, BK=32, 4 waves in 2x2, each wave 64x64 = 4x4 mfma 16x16x32.
#define BM 128
#define BN 128
#define BK 32

__global__ __launch_bounds__(256) void gemm_nce_kernel(
        const unsigned short* __restrict__ A,
        const unsigned short* __restrict__ Bt,
        const float* __restrict__ bn,
        const float* __restrict__ un,
        float* __restrict__ pmn,
        float* __restrict__ pnn) {
    __shared__ unsigned short As[BM * BK];   // 8 KB
    __shared__ unsigned short Bs[BN * BK];   // 8 KB

    const int tid  = threadIdx.x;
    const int lane = tid & 63;
    const int wave = tid >> 6;           // 0..3
    const int wm = wave & 1;             // wave row (2)
    const int wn = wave >> 1;            // wave col (2)
    const int row0 = blockIdx.x * BM;    // gridDim.x = 64
    const int col0 = blockIdx.y * BN;    // gridDim.y = 32

    const int r = lane & 15;             // fragment row/col within 16
    const int q = lane >> 4;             // quad 0..3

    f32x4 acc[4][4];
    #pragma unroll
    for (int mi = 0; mi < 4; mi++)
        #pragma unroll
        for (int ni = 0; ni < 4; ni++)
            acc[mi][ni] = (f32x4){0.f, 0.f, 0.f, 0.f};

    // staging: 512 chunks of 16B per matrix tile (128 rows x 4 chunks/row)
    const int c0  = tid;
    const int c1  = tid + 256;
    const int rr0 = c0 >> 2, cc0 = (c0 & 3) * 8;
    const int rr1 = c1 >> 2, cc1 = (c1 & 3) * 8;

    for (int k0 = 0; k0 < HDIM; k0 += BK) {
        *(uint4*)(&As[rr0 * BK + cc0]) = *(const uint4*)(&A[(size_t)(row0 + rr0) * HDIM + k0 + cc0]);
        *(uint4*)(&As[rr1 * BK + cc1]) = *(const uint4*)(&A[(size_t)(row0 + rr1) * HDIM + k0 + cc1]);
        *(uint4*)(&Bs[rr0 * BK + cc0]) = *(const uint4*)(&Bt[(size_t)(col0 + rr0) * HDIM + k0 + cc0]);
        *(uint4*)(&Bs[rr1 * BK + cc1]) = *(const uint4*)(&Bt[(size_t)(col0 + rr1) * HDIM + k0 + cc1]);
        __syncthreads();

        bf16x8 af[4], bfr[4];
        #pragma unroll
        for (int mi = 0; mi < 4; mi++)
            af[mi] = *(const bf16x8*)(&As[(wm * 64 + mi * 16 + r) * BK + q * 8]);
        #pragma unroll
        for (int ni = 0; ni < 4; ni++)
            bfr[ni] = *(const bf16x8*)(&Bs[(wn * 64 + ni * 16 + r) * BK + q * 8]);

        #pragma unroll
        for (int mi = 0; mi < 4; mi++)
            #pragma unroll
            for (int ni = 0; ni < 4; ni++)
                acc[mi][ni] = __builtin_amdgcn_mfma_f32_16x16x32_bf16(af[mi], bfr[ni], acc[mi][ni], 0, 0, 0);

        __syncthreads();
    }

    // epilogue: C/D layout col = lane&15, row = q*4 + reg
    float bnv[4], unv[4];
    #pragma unroll
    for (int ni = 0; ni < 4; ni++) {
        int cg = col0 + wn * 64 + ni * 16 + r;
        bnv[ni] = bn[cg];
        unv[ni] = un[cg];
    }
    #pragma unroll
    for (int mi = 0; mi < 4; mi++) {
        int rg0 = row0 + wm * 64 + mi * 16 + q * 4;
        #pragma unroll
        for (int ni = 0; ni < 4; ni++) {
            int cg = col0 + wn * 64 + ni * 16 + r;
            #pragma unroll
            for (int j = 0; j < 4; j++) {
                size_t off = (size_t)(rg0 + j) * KNOISE + cg;
                pmn[off] = __expf(acc[mi][ni][j] + bnv[ni]);
                pnn[off] = unv[ni];
            }
        }
    }
}

// ---------------------------------------------------------------------------
extern "C" void kernel_launch(void* const* d_in, const int* in_sizes, int n_in,
                              void* d_out, int out_size, void* d_ws, size_t ws_size,
                              hipStream_t stream) {
    const float* input   = (const float*)d_in[0];
    const float* weight  = (const float*)d_in[1];
    const float* bias    = (const float*)d_in[2];
    const float* unigram = (const float*)d_in[3];
    const int*   target  = (const int*)d_in[4];
    const int*   noise   = (const int*)d_in[5];

    // ws layout
    unsigned short* in_bf = (unsigned short*)d_ws;                    // 16 MB
    unsigned short* wn_bf = in_bf + (size_t)NROWS * HDIM;             // 8 MB
    float* bn = (float*)(wn_bf + (size_t)KNOISE * HDIM);              // 16 KB
    float* un = bn + KNOISE;                                          // 16 KB

    // out layout: pmt [N], pnt [N], pmn [N*K], pnn [N*K]
    float* out = (float*)d_out;
    float* o_pmt = out;
    float* o_pnt = out + NROWS;
    float* o_pmn = out + 2 * NROWS;
    float* o_pnn = o_pmn + (size_t)NROWS * KNOISE;

    conv_input_kernel<<<(NROWS * HDIM / 4) / 256, 256, 0, stream>>>(input, in_bf);
    gather_noise_kernel<<<KNOISE, 256, 0, stream>>>(weight, bias, unigram, noise, wn_bf, bn, un);
    pmt_kernel<<<NROWS, 256, 0, stream>>>(input, weight, bias, unigram, target, o_pmt, o_pnt);

    dim3 grid(NROWS / BM, KNOISE / BN);
    gemm_nce_kernel<<<grid, 256, 0, stream>>>(in_bf, wn_bf, bn, un, o_pmn, o_pnn);
}

// Round 2
// 476.640 us; speedup vs baseline: 1.1019x; 1.1019x over previous
//
#include <hip/hip_runtime.h>
#include <hip/hip_bf16.h>

// Problem constants (linear_nce): N=8192, H=1024, V=50257, K=4096
#define NROWS 8192
#define HDIM  1024
#define VDIM  50257
#define KNOISE 4096

typedef short  bf16x8 __attribute__((ext_vector_type(8)));
typedef float  f32x4  __attribute__((ext_vector_type(4)));

__device__ __forceinline__ unsigned short f2bf(float x) {
    union { float f; unsigned int u; } v; v.f = x;
    unsigned int r = (v.u + 0x7fffu + ((v.u >> 16) & 1u)) >> 16;
    return (unsigned short)r;
}

// async global->LDS 16B copy: LDS dest is wave-uniform base + lane*16
__device__ __forceinline__ void gload16(const void* g, void* l) {
    __builtin_amdgcn_global_load_lds(
        (const __attribute__((address_space(1))) void*)g,
        (__attribute__((address_space(3))) void*)l, 16, 0, 0);
}

// ---------------------------------------------------------------------------
// Fused prep kernel:
//  blocks [0, NROWS):          pmt/pnt fp32 dot for row b; also convert input
//                              row -> bf16 into in_bf (saves a separate pass).
//  blocks [NROWS, NROWS+K):    gather weight[noise] -> bf16 wn_bf, bn, un.
__global__ __launch_bounds__(256) void prep_kernel(
        const float* __restrict__ input,
        const float* __restrict__ weight,
        const float* __restrict__ bias,
        const float* __restrict__ unigram,
        const int* __restrict__ target,
        const int* __restrict__ noise,
        unsigned short* __restrict__ in_bf,
        unsigned short* __restrict__ wn_bf,
        float* __restrict__ bn,
        float* __restrict__ un,
        float* __restrict__ out_pmt,
        float* __restrict__ out_pnt) {
    const int tid = threadIdx.x;
    if (blockIdx.x < NROWS) {
        const int row = blockIdx.x;
        const int t = target[row];
        float4 a = ((const float4*)(input + (size_t)row * HDIM))[tid];
        // fold the fp32->bf16 conversion of `input` into this kernel
        ushort4 o;
        o.x = f2bf(a.x); o.y = f2bf(a.y); o.z = f2bf(a.z); o.w = f2bf(a.w);
        ((ushort4*)(in_bf + (size_t)row * HDIM))[tid] = o;
        float4 w = ((const float4*)(weight + (size_t)t * HDIM))[tid];
        float s = a.x * w.x + a.y * w.y + a.z * w.z + a.w * w.w;
        #pragma unroll
        for (int off = 32; off > 0; off >>= 1) s += __shfl_down(s, off);
        __shared__ float red[4];
        if ((tid & 63) == 0) red[tid >> 6] = s;
        __syncthreads();
        if (tid == 0) {
            float tot = red[0] + red[1] + red[2] + red[3];
            out_pmt[row] = expf(tot + bias[t]);
            out_pnt[row] = unigram[t];
        }
    } else {
        const int r = blockIdx.x - NROWS;       // 0..K-1
        const int idx = noise[r];
        float4 v = ((const float4*)(weight + (size_t)idx * HDIM))[tid];
        ushort4 o;
        o.x = f2bf(v.x); o.y = f2bf(v.y); o.z = f2bf(v.z); o.w = f2bf(v.w);
        ((ushort4*)(wn_bf + (size_t)r * HDIM))[tid] = o;
        if (tid == 0) { bn[r] = bias[idx]; un[r] = unigram[idx]; }
    }
}

// ---------------------------------------------------------------------------
// GEMM: pmn = exp(A @ Bt^T + bn), pnn = broadcast(un)
// A [8192x1024] bf16, Bt [4096x1024] bf16. 128x128 tile, BK=32, 4 waves 2x2,
// each wave 64x64 via 4x4 mfma_f32_16x16x32_bf16. global_load_lds staging.
#define BM 128
#define BN 128
#define BK 32
// epilogue transpose: per-wave 16 rows x 68 floats (pad 64->68 kills conflicts)
#define EPS_LD 68
#define EPS_WAVE (16 * EPS_LD)   // 1088 floats = 4352 B
#define SMEM_BYTES (4 * EPS_WAVE * 4)  // 17408 B >= 16384 B tile usage

__global__ __launch_bounds__(256) void gemm_nce_kernel(
        const unsigned short* __restrict__ A,
        const unsigned short* __restrict__ Bt,
        const float* __restrict__ bn,
        const float* __restrict__ un,
        float* __restrict__ pmn,
        float* __restrict__ pnn) {
    __shared__ char smem[SMEM_BYTES];
    unsigned short* As = (unsigned short*)smem;            // 8192 B
    unsigned short* Bs = (unsigned short*)(smem + BM * BK * 2); // 8192 B

    const int tid  = threadIdx.x;
    const int lane = tid & 63;
    const int wave = tid >> 6;           // 0..3
    const int wm = wave & 1;
    const int wn = wave >> 1;
    const int row0 = blockIdx.x * BM;    // gridDim.x = 64
    const int col0 = blockIdx.y * BN;    // gridDim.y = 32

    const int r = lane & 15;
    const int q = lane >> 4;

    f32x4 acc[4][4];
    #pragma unroll
    for (int mi = 0; mi < 4; mi++)
        #pragma unroll
        for (int ni = 0; ni < 4; ni++)
            acc[mi][ni] = (f32x4){0.f, 0.f, 0.f, 0.f};

    // staging: each wave stages 2 chunks of 16 rows for As, same for Bs.
    // chunk = 16 rows x 64 B = 1024 B = 64 lanes x 16 B, lane-linear row-major.
    const int ch0 = wave * 2;
    const int ch1 = wave * 2 + 1;
    const int lr = lane >> 2;            // row within chunk
    const int lc = (lane & 3) * 8;       // element col within row
    const unsigned short* aT = A  + (size_t)row0 * HDIM;
    const unsigned short* bT = Bt + (size_t)col0 * HDIM;
    const unsigned short* ga0 = aT + (size_t)(ch0 * 16 + lr) * HDIM + lc;
    const unsigned short* ga1 = aT + (size_t)(ch1 * 16 + lr) * HDIM + lc;
    const unsigned short* gb0 = bT + (size_t)(ch0 * 16 + lr) * HDIM + lc;
    const unsigned short* gb1 = bT + (size_t)(ch1 * 16 + lr) * HDIM + lc;

    for (int k0 = 0; k0 < HDIM; k0 += BK) {
        gload16(ga0 + k0, &As[ch0 * 512]);
        gload16(ga1 + k0, &As[ch1 * 512]);
        gload16(gb0 + k0, &Bs[ch0 * 512]);
        gload16(gb1 + k0, &Bs[ch1 * 512]);
        __syncthreads();

        bf16x8 af[4], bfr[4];
        #pragma unroll
        for (int mi = 0; mi < 4; mi++)
            af[mi] = *(const bf16x8*)(&As[(wm * 64 + mi * 16 + r) * BK + q * 8]);
        #pragma unroll
        for (int ni = 0; ni < 4; ni++)
            bfr[ni] = *(const bf16x8*)(&Bs[(wn * 64 + ni * 16 + r) * BK + q * 8]);

        #pragma unroll
        for (int mi = 0; mi < 4; mi++)
            #pragma unroll
            for (int ni = 0; ni < 4; ni++)
                acc[mi][ni] = __builtin_amdgcn_mfma_f32_16x16x32_bf16(af[mi], bfr[ni], acc[mi][ni], 0, 0, 0);

        __syncthreads();
    }

    // ---- epilogue ----
    // per-wave LDS region for the 16x64 transpose (row stride 68 floats)
    float* eps = (float*)smem + wave * EPS_WAVE;

    float bnv[4];
    #pragma unroll
    for (int ni = 0; ni < 4; ni++)
        bnv[ni] = bn[col0 + wn * 64 + ni * 16 + r];

    const int rrd = lane >> 4;           // read-side row group 0..3
    const int crd = (lane & 15) * 4;     // read-side col 0..63 step 4
    float4 unv4 = *(const float4*)&un[col0 + wn * 64 + crd];

    #pragma unroll
    for (int mi = 0; mi < 4; mi++) {
        // write exp(acc+bias) into LDS: [row16 = q*4+j][col64 = ni*16+r]
        #pragma unroll
        for (int ni = 0; ni < 4; ni++)
            #pragma unroll
            for (int j = 0; j < 4; j++)
                eps[(q * 4 + j) * EPS_LD + ni * 16 + r] = __expf(acc[mi][ni][j] + bnv[ni]);
        __builtin_amdgcn_s_waitcnt(0);   // lgkm drain within wave (cheap, safe)
        // read transposed: lane covers row rrd*4+j, cols crd..crd+3
        #pragma unroll
        for (int j = 0; j < 4; j++) {
            float4 v = *(float4*)&eps[(rrd * 4 + j) * EPS_LD + crd];
            size_t off = (size_t)(row0 + wm * 64 + mi * 16 + rrd * 4 + j) * KNOISE
                       + col0 + wn * 64 + crd;
            *(float4*)&pmn[off] = v;
        }
    }

    // pnn = broadcast(un): 16 float4 stores per lane, 256B contiguous per row
    #pragma unroll
    for (int t = 0; t < 16; t++) {
        int rr = rrd + 4 * t;            // 0..63
        size_t off = (size_t)(row0 + wm * 64 + rr) * KNOISE + col0 + wn * 64 + crd;
        *(float4*)&pnn[off] = unv4;
    }
}

// ---------------------------------------------------------------------------
extern "C" void kernel_launch(void* const* d_in, const int* in_sizes, int n_in,
                              void* d_out, int out_size, void* d_ws, size_t ws_size,
                              hipStream_t stream) {
    const float* input   = (const float*)d_in[0];
    const float* weight  = (const float*)d_in[1];
    const float* bias    = (const float*)d_in[2];
    const float* unigram = (const float*)d_in[3];
    const int*   target  = (const int*)d_in[4];
    const int*   noise   = (const int*)d_in[5];

    unsigned short* in_bf = (unsigned short*)d_ws;                    // 16 MB
    unsigned short* wn_bf = in_bf + (size_t)NROWS * HDIM;             // 8 MB
    float* bn = (float*)(wn_bf + (size_t)KNOISE * HDIM);
    float* un = bn + KNOISE;

    float* out = (float*)d_out;
    float* o_pmt = out;
    float* o_pnt = out + NROWS;
    float* o_pmn = out + 2 * NROWS;
    float* o_pnn = o_pmn + (size_t)NROWS * KNOISE;

    prep_kernel<<<NROWS + KNOISE, 256, 0, stream>>>(
        input, weight, bias, unigram, target, noise,
        in_bf, wn_bf, bn, un, o_pmt, o_pnt);

    dim3 grid(NROWS / BM, KNOISE / BN);
    gemm_nce_kernel<<<grid, 256, 0, stream>>>(in_bf, wn_bf, bn, un, o_pmn, o_pnn);
}

// Round 3
// 467.806 us; speedup vs baseline: 1.1227x; 1.0189x over previous
//
#include <hip/hip_runtime.h>
#include <hip/hip_bf16.h>

// Problem constants (linear_nce): N=8192, H=1024, V=50257, K=4096
#define NROWS 8192
#define HDIM  1024
#define VDIM  50257
#define KNOISE 4096

typedef short  bf16x8 __attribute__((ext_vector_type(8)));
typedef float  f32x4  __attribute__((ext_vector_type(4)));

__device__ __forceinline__ unsigned short f2bf(float x) {
    union { float f; unsigned int u; } v; v.f = x;
    unsigned int r = (v.u + 0x7fffu + ((v.u >> 16) & 1u)) >> 16;
    return (unsigned short)r;
}

// async global->LDS 16B copy: LDS dest is wave-uniform base + lane*16
__device__ __forceinline__ void gload16(const void* g, void* l) {
    __builtin_amdgcn_global_load_lds(
        (const __attribute__((address_space(1))) void*)g,
        (__attribute__((address_space(3))) void*)l, 16, 0, 0);
}

// ---------------------------------------------------------------------------
// Fused prep kernel:
//  blocks [0, NROWS):       pmt/pnt fp32 dot for row b; also convert input row
//                           -> bf16 into in_bf.
//  blocks [NROWS, NROWS+K): gather weight[noise] -> bf16 wn_bf, bn, un.
__global__ __launch_bounds__(256) void prep_kernel(
        const float* __restrict__ input,
        const float* __restrict__ weight,
        const float* __restrict__ bias,
        const float* __restrict__ unigram,
        const int* __restrict__ target,
        const int* __restrict__ noise,
        unsigned short* __restrict__ in_bf,
        unsigned short* __restrict__ wn_bf,
        float* __restrict__ bn,
        float* __restrict__ un,
        float* __restrict__ out_pmt,
        float* __restrict__ out_pnt) {
    const int tid = threadIdx.x;
    if (blockIdx.x < NROWS) {
        const int row = blockIdx.x;
        const int t = target[row];
        float4 a = ((const float4*)(input + (size_t)row * HDIM))[tid];
        ushort4 o;
        o.x = f2bf(a.x); o.y = f2bf(a.y); o.z = f2bf(a.z); o.w = f2bf(a.w);
        ((ushort4*)(in_bf + (size_t)row * HDIM))[tid] = o;
        float4 w = ((const float4*)(weight + (size_t)t * HDIM))[tid];
        float s = a.x * w.x + a.y * w.y + a.z * w.z + a.w * w.w;
        #pragma unroll
        for (int off = 32; off > 0; off >>= 1) s += __shfl_down(s, off);
        __shared__ float red[4];
        if ((tid & 63) == 0) red[tid >> 6] = s;
        __syncthreads();
        if (tid == 0) {
            float tot = red[0] + red[1] + red[2] + red[3];
            out_pmt[row] = expf(tot + bias[t]);
            out_pnt[row] = unigram[t];
        }
    } else {
        const int r = blockIdx.x - NROWS;       // 0..K-1
        const int idx = noise[r];
        float4 v = ((const float4*)(weight + (size_t)idx * HDIM))[tid];
        ushort4 o;
        o.x = f2bf(v.x); o.y = f2bf(v.y); o.z = f2bf(v.z); o.w = f2bf(v.w);
        ((ushort4*)(wn_bf + (size_t)r * HDIM))[tid] = o;
        if (tid == 0) { bn[r] = bias[idx]; un[r] = unigram[idx]; }
    }
}

// ---------------------------------------------------------------------------
// GEMM: pmn = exp(A @ Bt^T + bn), pnn = broadcast(un)
// 128x128 tile, BK=64 as two stacked 32-col panels (each panel keeps the
// lane-linear global_load_lds layout). 4 waves 2x2, wave tile 64x64 via 4x4
// mfma_f32_16x16x32_bf16. pnn stores interleaved into the K-loop.
#define BM 128
#define BN 128
// epilogue transpose: per-wave 16 rows x 68 floats (pad 64->68)
#define EPS_LD 68
#define EPS_WAVE (16 * EPS_LD)
#define SMEM_BYTES 32768   // 2 panels x (128x32) bf16 x 2 matrices

__global__ __launch_bounds__(256) void gemm_nce_kernel(
        const unsigned short* __restrict__ A,
        const unsigned short* __restrict__ Bt,
        const float* __restrict__ bn,
        const float* __restrict__ un,
        float* __restrict__ pmn,
        float* __restrict__ pnn) {
    __shared__ char smem[SMEM_BYTES];
    unsigned short* As = (unsigned short*)smem;              // 2 x 4096 elems
    unsigned short* Bs = (unsigned short*)(smem + 16384);    // 2 x 4096 elems

    const int tid  = threadIdx.x;
    const int lane = tid & 63;
    const int wave = tid >> 6;
    const int wm = wave & 1;
    const int wn = wave >> 1;
    const int row0 = blockIdx.x * BM;    // gridDim.x = 64
    const int col0 = blockIdx.y * BN;    // gridDim.y = 32

    const int r = lane & 15;
    const int q = lane >> 4;

    f32x4 acc[4][4];
    #pragma unroll
    for (int mi = 0; mi < 4; mi++)
        #pragma unroll
        for (int ni = 0; ni < 4; ni++)
            acc[mi][ni] = (f32x4){0.f, 0.f, 0.f, 0.f};

    // staging: per wave, 2 chunks of 16 rows for each matrix, per 32-col panel.
    const int ch0 = wave * 2;
    const int ch1 = wave * 2 + 1;
    const int lr = lane >> 2;            // row within 16-row chunk
    const int lc = (lane & 3) * 8;       // col (elements) within 32-col panel
    const unsigned short* aT = A  + (size_t)row0 * HDIM;
    const unsigned short* bT = Bt + (size_t)col0 * HDIM;
    const unsigned short* ga0 = aT + (size_t)(ch0 * 16 + lr) * HDIM + lc;
    const unsigned short* ga1 = aT + (size_t)(ch1 * 16 + lr) * HDIM + lc;
    const unsigned short* gb0 = bT + (size_t)(ch0 * 16 + lr) * HDIM + lc;
    const unsigned short* gb1 = bT + (size_t)(ch1 * 16 + lr) * HDIM + lc;

    // epilogue / pnn-store lane mapping (read side of the transpose)
    const int rrd = lane >> 4;           // 0..3
    const int crd = (lane & 15) * 4;     // 0..60
    const float4 unv4 = *(const float4*)&un[col0 + wn * 64 + crd];
    float* pnn_base = pnn + (size_t)(row0 + wm * 64) * KNOISE + col0 + wn * 64 + crd;

    for (int k0 = 0; k0 < HDIM; k0 += 64) {
        gload16(ga0 + k0,      &As[ch0 * 512]);
        gload16(ga1 + k0,      &As[ch1 * 512]);
        gload16(ga0 + k0 + 32, &As[4096 + ch0 * 512]);
        gload16(ga1 + k0 + 32, &As[4096 + ch1 * 512]);
        gload16(gb0 + k0,      &Bs[ch0 * 512]);
        gload16(gb1 + k0,      &Bs[ch1 * 512]);
        gload16(gb0 + k0 + 32, &Bs[4096 + ch0 * 512]);
        gload16(gb1 + k0 + 32, &Bs[4096 + ch1 * 512]);
        __syncthreads();

        #pragma unroll
        for (int p = 0; p < 2; p++) {
            bf16x8 af[4], bfr[4];
            #pragma unroll
            for (int mi = 0; mi < 4; mi++)
                af[mi] = *(const bf16x8*)(&As[p * 4096 + (wm * 64 + mi * 16 + r) * 32 + q * 8]);
            #pragma unroll
            for (int ni = 0; ni < 4; ni++)
                bfr[ni] = *(const bf16x8*)(&Bs[p * 4096 + (wn * 64 + ni * 16 + r) * 32 + q * 8]);
            #pragma unroll
            for (int mi = 0; mi < 4; mi++)
                #pragma unroll
                for (int ni = 0; ni < 4; ni++)
                    acc[mi][ni] = __builtin_amdgcn_mfma_f32_16x16x32_bf16(af[mi], bfr[ni], acc[mi][ni], 0, 0, 0);
        }

        // interleaved pnn broadcast store: 1 float4/lane/iter, 16 iters cover
        // the wave's 64 rows. Independent of acc; rides idle store BW.
        {
            int t = k0 >> 6;             // 0..15
            *(float4*)&pnn_base[(size_t)(rrd + 4 * t) * KNOISE] = unv4;
        }
        __syncthreads();
    }

    // ---- epilogue: exp(acc+bias) -> LDS transpose -> float4 stores ----
    float* eps = (float*)smem + wave * EPS_WAVE;

    float bnv[4];
    #pragma unroll
    for (int ni = 0; ni < 4; ni++)
        bnv[ni] = bn[col0 + wn * 64 + ni * 16 + r];

    #pragma unroll
    for (int mi = 0; mi < 4; mi++) {
        #pragma unroll
        for (int ni = 0; ni < 4; ni++)
            #pragma unroll
            for (int j = 0; j < 4; j++)
                eps[(q * 4 + j) * EPS_LD + ni * 16 + r] = __expf(acc[mi][ni][j] + bnv[ni]);
        __builtin_amdgcn_s_waitcnt(0xc07f);   // lgkmcnt(0) only — don't drain pnn stores
        #pragma unroll
        for (int j = 0; j < 4; j++) {
            float4 v = *(float4*)&eps[(rrd * 4 + j) * EPS_LD + crd];
            size_t off = (size_t)(row0 + wm * 64 + mi * 16 + rrd * 4 + j) * KNOISE
                       + col0 + wn * 64 + crd;
            *(float4*)&pmn[off] = v;
        }
        __builtin_amdgcn_s_waitcnt(0xc07f);   // reads done before next mi overwrites
    }
}

// ---------------------------------------------------------------------------
extern "C" void kernel_launch(void* const* d_in, const int* in_sizes, int n_in,
                              void* d_out, int out_size, void* d_ws, size_t ws_size,
                              hipStream_t stream) {
    const float* input   = (const float*)d_in[0];
    const float* weight  = (const float*)d_in[1];
    const float* bias    = (const float*)d_in[2];
    const float* unigram = (const float*)d_in[3];
    const int*   target  = (const int*)d_in[4];
    const int*   noise   = (const int*)d_in[5];

    unsigned short* in_bf = (unsigned short*)d_ws;                    // 16 MB
    unsigned short* wn_bf = in_bf + (size_t)NROWS * HDIM;             // 8 MB
    float* bn = (float*)(wn_bf + (size_t)KNOISE * HDIM);
    float* un = bn + KNOISE;

    float* out = (float*)d_out;
    float* o_pmt = out;
    float* o_pnt = out + NROWS;
    float* o_pmn = out + 2 * NROWS;
    float* o_pnn = o_pmn + (size_t)NROWS * KNOISE;

    prep_kernel<<<NROWS + KNOISE, 256, 0, stream>>>(
        input, weight, bias, unigram, target, noise,
        in_bf, wn_bf, bn, un, o_pmt, o_pnt);

    dim3 grid(NROWS / BM, KNOISE / BN);
    gemm_nce_kernel<<<grid, 256, 0, stream>>>(in_bf, wn_bf, bn, un, o_pmn, o_pnn);
}